// Round 9
// baseline (169.404 us; speedup 1.0000x reference)
//
#include <hip/hip_runtime.h>

#define NROWS 65536
#define DIM 64
#define KCODES 8192
#define DECAYF 0.99f
#define EPSV 1e-5f
#define KD (KCODES * DIM)
#define KSPLIT 4
#define KC (KCODES / KSPLIT)   // 2048 codes per split chunk
#define NTILES (KC / 32)       // 64 tiles of 32 codes

typedef _Float16 half8 __attribute__((ext_vector_type(8)));
typedef float f32x16 __attribute__((ext_vector_type(16)));

// ws layout (float offsets) — total ~3.6 MB
#define WS_STATS  0          // 256: mean[64], rstd[64], running_std[64]
#define WS_NHCK   256        // 8192: 10.6875 - 0.5*||e_k||^2 (centered)
#define WS_EBUF   8448       // 262144: 8192 codes x 64 dims f16 (1 MB), tiled layout
#define WS_PSUM   270592     // 16384
#define WS_PSQ    286976     // 16384
#define WS_PACKED 303360     // 65536 u32: flip(score w/ key in low 13 bits)
#define WS_DW     368896     // 8192*64
#define WS_COUNTS 893184     // 8192  (PACKED..COUNTS contiguous: single memset)

// ---------------- K1a: per-block column partial sums ----------------
__global__ __launch_bounds__(256) void k_colstats_partial(
    const float* __restrict__ x, float* __restrict__ psum, float* __restrict__ psq)
{
    const int wave = threadIdx.x >> 6;
    const int col  = threadIdx.x & 63;
    const int base = blockIdx.x * 256;
    float s = 0.f, q = 0.f;
    #pragma unroll 4
    for (int i = 0; i < 64; ++i) {
        int r = base + i * 4 + wave;
        float v = x[(size_t)r * DIM + col];
        s += v;
        q += v * v;
    }
    __shared__ float ls[4][64];
    __shared__ float lq[4][64];
    ls[wave][col] = s;
    lq[wave][col] = q;
    __syncthreads();
    if (threadIdx.x < 64) {
        psum[blockIdx.x * 64 + col] = ls[0][col] + ls[1][col] + ls[2][col] + ls[3][col];
        psq[blockIdx.x * 64 + col]  = lq[0][col] + lq[1][col] + lq[2][col] + lq[3][col];
    }
}

// ---------------- K1b: finalize stats ----------------
__global__ void k_colstats_final(const float* __restrict__ psum,
                                 const float* __restrict__ psq,
                                 float* __restrict__ stats)
{
    const int col = threadIdx.x; // 64 threads
    float s = 0.f, q = 0.f;
    for (int i = 0; i < 256; ++i) {
        s += psum[i * 64 + col];
        q += psq[i * 64 + col];
    }
    const float n = (float)NROWS;
    float mean = s / n;
    float var = q / n - mean * mean;
    if (var < 0.f) var = 0.f;
    stats[col]       = mean;
    stats[64 + col]  = 1.0f / sqrtf(var + EPSV);
    stats[128 + col] = sqrtf(var * (n / (n - 1.0f)) + EPSV);
}

// ---------------- K2: prep emb (f16 centered plane, tiled layout) + nhck --
// ebuf layout (half8 units): idx = T*256 + c*64 + h*32 + col
//   code = T*32 + col ; element dims = c*16 + h*8 + j
__global__ __launch_bounds__(256) void k_prep(const float* __restrict__ emb,
                                              half8* __restrict__ ebuf,
                                              float* __restrict__ nhck)
{
    const int tid = blockIdx.x * 256 + threadIdx.x;   // 65536 = 8192 codes * 8
    const int code = tid >> 3, sub = tid & 7;
    const int c = sub >> 1, h = sub & 1;
    const int d0 = c * 16 + h * 8;
    const float* e = emb + (size_t)code * DIM + d0;
    float4 a = *(const float4*)e;
    float4 b = *(const float4*)(e + 4);
    float f[8] = {a.x, a.y, a.z, a.w, b.x, b.y, b.z, b.w};
    half8 hh;
    float ssq = 0.f;
    #pragma unroll
    for (int i = 0; i < 8; ++i) {
        hh[i] = (_Float16)(f[i] - 0.5f);   // centered: halves f16 quantization err
        ssq += f[i] * f[i];
    }
    #pragma unroll
    for (int o = 1; o < 8; o <<= 1) ssq += __shfl_xor(ssq, o, 64);
    // centered score bias: keeps |score| small so the low-13-bit key
    // corruption (bfi-max trick) stays ~1e-3
    if (sub == 0) nhck[code] = 10.6875f - 0.5f * ssq;
    const int T = code >> 5, col = code & 31;
    ebuf[(size_t)T * 256 + c * 64 + h * 32 + col] = hh;
}

// ---------------- K3: 32x32 MFMA distance argmin (no LDS, no barriers) ----
// 256 thr = 4 waves; wave owns 32 rows; block = 128 rows x KC codes.
// grid = (NROWS/128, KSPLIT). Single f16 plane.
// B fragments stream directly from L2 (ebuf = 1 MB, resident; 256 KB/chunk).
// No __syncthreads -> waves free-run in different phases so one wave's VALU
// (select) overlaps another's MFMA (separate pipes, m114). Occupancy limited
// by VGPR only.
// Maximizes w = f16(xn).f16(e-0.5) + nhck' (== argmin dist, score centered).
// Select: bfi-max — low 13 mantissa bits of the running best carry
// key = 8191-code (larger key = smaller code wins ties for w>=0).
__global__ __launch_bounds__(256) void k_argmin32(
    const float* __restrict__ x, const half8* __restrict__ ebuf,
    const float* __restrict__ nhckg, const float* __restrict__ stats,
    unsigned* __restrict__ packed)
{
    const int lane = threadIdx.x & 63;
    const int wave = threadIdx.x >> 6;
    const int kc = blockIdx.y;
    const int col = lane & 31, h = lane >> 5;
    const int myrow = blockIdx.x * 128 + wave * 32 + col;

    // ---- A fragments: single f16 plane of normalized row ----
    half8 ah[4];
    {
        const float* xr = x + (size_t)myrow * DIM + h * 8;
        #pragma unroll
        for (int c = 0; c < 4; ++c) {
            float4 v0  = *(const float4*)(xr + c * 16);
            float4 v1  = *(const float4*)(xr + c * 16 + 4);
            float4 mu0 = *(const float4*)(stats + h * 8 + c * 16);
            float4 mu1 = *(const float4*)(stats + h * 8 + c * 16 + 4);
            float4 sg0 = *(const float4*)(stats + 64 + h * 8 + c * 16);
            float4 sg1 = *(const float4*)(stats + 64 + h * 8 + c * 16 + 4);
            ah[c][0] = (_Float16)((v0.x - mu0.x) * sg0.x);
            ah[c][1] = (_Float16)((v0.y - mu0.y) * sg0.y);
            ah[c][2] = (_Float16)((v0.z - mu0.z) * sg0.z);
            ah[c][3] = (_Float16)((v0.w - mu0.w) * sg0.w);
            ah[c][4] = (_Float16)((v1.x - mu1.x) * sg1.x);
            ah[c][5] = (_Float16)((v1.y - mu1.y) * sg1.y);
            ah[c][6] = (_Float16)((v1.z - mu1.z) * sg1.z);
            ah[c][7] = (_Float16)((v1.w - mu1.w) * sg1.w);
        }
    }

    float best[16];
    #pragma unroll
    for (int i = 0; i < 16; ++i) best[i] = -3.4e38f;

    // per-lane bases (chunk kc: codes [kc*KC, kc*KC+KC))
    const half8* esrc = ebuf + (size_t)kc * (KC * 8) + h * 32 + col;
    const float* ckb = nhckg + kc * KC + col;
    const unsigned kbase = (unsigned)(8191 - kc * KC - col);

    #pragma unroll 2
    for (int T = 0; T < NTILES; ++T) {
        const half8* p = esrc + T * 256;
        half8 b0 = p[0];
        half8 b1 = p[64];
        half8 b2 = p[128];
        half8 b3 = p[192];
        float nv = ckb[T * 32];
        const unsigned key = kbase - (unsigned)(T * 32);
        f32x16 acc;
        #pragma unroll
        for (int i = 0; i < 16; ++i) acc[i] = nv;
        __builtin_amdgcn_s_setprio(1);
        acc = __builtin_amdgcn_mfma_f32_32x32x16_f16(ah[0], b0, acc, 0, 0, 0);
        acc = __builtin_amdgcn_mfma_f32_32x32x16_f16(ah[1], b1, acc, 0, 0, 0);
        acc = __builtin_amdgcn_mfma_f32_32x32x16_f16(ah[2], b2, acc, 0, 0, 0);
        acc = __builtin_amdgcn_mfma_f32_32x32x16_f16(ah[3], b3, acc, 0, 0, 0);
        __builtin_amdgcn_s_setprio(0);
        #pragma unroll
        for (int i = 0; i < 16; ++i) {
            unsigned u = (__float_as_uint(acc[i]) & 0xFFFFE000u) | key;
            best[i] = fmaxf(best[i], __uint_as_float(u));
        }
    }

    // cross-lane max over the 32 code columns (keys break ties -> no equals)
    #pragma unroll
    for (int off = 1; off < 32; off <<= 1) {
        #pragma unroll
        for (int i = 0; i < 16; ++i)
            best[i] = fmaxf(best[i], __shfl_xor(best[i], off, 64));
    }
    // publish per-row winner as sortable u32; atomicMax merges KSPLIT chunks.
    if (col == 0) {
        const int rbase = blockIdx.x * 128 + wave * 32 + 4 * h;
        #pragma unroll
        for (int i = 0; i < 16; ++i) {
            int row = rbase + (i & 3) + 8 * (i >> 2);
            unsigned u = __float_as_uint(best[i]);
            u = (u & 0x80000000u) ? ~u : (u | 0x80000000u);
            atomicMax(&packed[row], u);
        }
    }
}

// ---------------- K4: scatter (segment sums) + counts ----------------
__global__ __launch_bounds__(256) void k_scatter(
    const float* __restrict__ x, const float* __restrict__ stats,
    const unsigned* __restrict__ packed,
    float* __restrict__ dw, float* __restrict__ counts)
{
    const int t = blockIdx.x * 256 + threadIdx.x;
    const int row = t >> 6, col = t & 63;
    const unsigned v = packed[row];
    const unsigned key = (v & 0x80000000u) ? (v & 8191u) : (~v & 8191u);
    const int j = 8191 - (int)key;
    float xv = (x[(size_t)row * DIM + col] - stats[col]) * stats[64 + col];
    atomicAdd(&dw[(size_t)j * DIM + col], xv);
    if (col == 0) atomicAdd(&counts[j], 1.0f);
}

// ---------------- K5: epilogue ----------------
__global__ __launch_bounds__(256) void k_final(
    const float* __restrict__ emb, const float* __restrict__ cs,
    const float* __restrict__ dw, const float* __restrict__ counts,
    const float* __restrict__ stats, float* __restrict__ out)
{
    const int t = blockIdx.x * 256 + threadIdx.x; // over K*D
    const int k = t >> 6, d = t & 63;
    float csk = cs[k];
    float ns = csk * DECAYF + (1.f - DECAYF) * counts[k];
    float ne = (csk * emb[t] * DECAYF + (1.f - DECAYF) * dw[t]) / ns;
    out[KD + t] = ne;
    out[t] = ne * stats[128 + d] + stats[d];
    if (d == 0) out[2 * KD + k] = ns;
}

extern "C" void kernel_launch(void* const* d_in, const int* in_sizes, int n_in,
                              void* d_out, int out_size, void* d_ws, size_t ws_size,
                              hipStream_t stream)
{
    const float* x   = (const float*)d_in[0];
    const float* emb = (const float*)d_in[1];
    const float* cs  = (const float*)d_in[2];
    float* out = (float*)d_out;
    float* ws  = (float*)d_ws;

    float* stats  = ws + WS_STATS;
    float* nhck   = ws + WS_NHCK;
    half8* ebuf   = (half8*)(ws + WS_EBUF);
    float* psum   = ws + WS_PSUM;
    float* psq    = ws + WS_PSQ;
    unsigned* packed = (unsigned*)(ws + WS_PACKED);
    float* dw     = ws + WS_DW;
    float* counts = ws + WS_COUNTS;

    // zero packed + dw + counts (contiguous) in one shot
    hipMemsetAsync(ws + WS_PACKED, 0,
                   (size_t)(65536 + KD + KCODES) * sizeof(float), stream);

    k_colstats_partial<<<256, 256, 0, stream>>>(x, psum, psq);
    k_colstats_final<<<1, 64, 0, stream>>>(psum, psq, stats);
    k_prep<<<256, 256, 0, stream>>>(emb, ebuf, nhck);
    dim3 g3(NROWS / 128, KSPLIT);
    k_argmin32<<<g3, 256, 0, stream>>>(x, ebuf, nhck, stats, packed);
    k_scatter<<<(NROWS * DIM) / 256, 256, 0, stream>>>(x, stats, packed, dw, counts);
    k_final<<<KD / 256, 256, 0, stream>>>(emb, cs, dw, counts, stats, out);
}